// Round 8
// baseline (140.837 us; speedup 1.0000x reference)
//
#include <hip/hip_runtime.h>
#include <hip/hip_bf16.h>

#define HW_TOTAL 16384
#define C2 128
#define PPBG 16                          // pixels per group
#define NGRP 4                           // pixel-groups per block (1024 threads)
#define NBLK (HW_TOTAL / (PPBG * NGRP))  // 256 blocks = 1 per CU

#define WLDS_USH (3 * 128 * 128)         // 49152 ushort = 96 KiB swizzled weights
#define TILE_USH (16 * 136)              // bf16 pixel tile (+pad)
#define LDS_BYTES ((WLDS_USH + NGRP * 2 * TILE_USH) * 2)   // 133120 B

typedef short bf16x8 __attribute__((ext_vector_type(8)));
typedef float f32x4 __attribute__((ext_vector_type(4)));

__device__ __forceinline__ unsigned pk2bf(float lo, float hi) {
    __hip_bfloat162 h = __float22bfloat162_rn(make_float2(lo, hi));
    union { __hip_bfloat162 h; unsigned u; } v; v.h = h;
    return v.u;
}
__device__ __forceinline__ unsigned short f2bf(float f) {
    union { float f; unsigned u; } v; v.f = f;
    unsigned r = v.u + 0x7FFFu + ((v.u >> 16) & 1u);
    return (unsigned short)(r >> 16);
}
__device__ __forceinline__ float fast_sigmoid(float x) {
    return __builtin_amdgcn_rcpf(1.0f + __expf(-x));
}
__device__ __forceinline__ float fast_softplus(float x) {
    return fmaxf(x, 0.0f) + __logf(1.0f + __expf(-fabsf(x)));
}
// barrier WITHOUT vmcnt(0) drain: LDS is the only cross-thread medium in the loop.
__device__ __forceinline__ void block_sync_lds() {
    asm volatile("s_waitcnt lgkmcnt(0)\n\ts_barrier" ::: "memory");
}

// ---- Kernel 1: separable DFT of padded 7x7 kernels -> field[hw][c] = (Ar,Ai,0.1*Br,0.1*Bi) ----
__global__ void field_kernel(const float* __restrict__ Ark, const float* __restrict__ Aik,
                             const float* __restrict__ Brk, const float* __restrict__ Bik,
                             float4* __restrict__ field) {
    __shared__ float2 tw[128];
    __shared__ float2 G[2][64][9];
    const int v = blockIdx.x >> 1;
    const int uhalf = blockIdx.x & 1;
    const int t = threadIdx.x;
    if (t < 128) {
        float ph = (float)t * (6.283185307179586f / 128.0f);
        tw[t] = make_float2(cosf(ph), sinf(ph));
    }
    __syncthreads();
    for (int e = t; e < 896; e += 256) {
        const int kern = (e >= 448) ? 1 : 0;
        const int rem = e - kern * 448;
        const int c = rem / 7, p = rem % 7;
        const float* kr = kern ? Brk : Ark;
        const float* ki = kern ? Bik : Aik;
        float gr = 0.f, gi = 0.f;
#pragma unroll
        for (int q = 0; q < 7; ++q) {
            const int idx = (v * (q + 60)) & 127;
            const float twr = tw[idx].x, twi = -tw[idx].y;
            const float ar = kr[c * 49 + p * 7 + q], ai = ki[c * 49 + p * 7 + q];
            gr += ar * twr - ai * twi;
            gi += ar * twi + ai * twr;
        }
        G[kern][c][p] = make_float2(gr, gi);
    }
    __syncthreads();
    const int c = t & 63, ug = t >> 6;
    float2 gA[7], gB[7];
#pragma unroll
    for (int p = 0; p < 7; ++p) { gA[p] = G[0][c][p]; gB[p] = G[1][c][p]; }
    for (int k = 0; k < 16; ++k) {
        const int u = uhalf * 64 + ug * 16 + k;
        float Are = 0.f, Aim = 0.f, Bre = 0.f, Bim = 0.f;
#pragma unroll
        for (int p = 0; p < 7; ++p) {
            const int idx = (u * (p + 60)) & 127;
            const float twr = tw[idx].x, twi = -tw[idx].y;
            Are += gA[p].x * twr - gA[p].y * twi;
            Aim += gA[p].x * twi + gA[p].y * twr;
            Bre += gB[p].x * twr - gB[p].y * twi;
            Bim += gB[p].x * twi + gB[p].y * twr;
        }
        const float mag = sqrtf(Are * Are + Aim * Aim + 1e-8f);
        const float scale = 0.95f * (1.0f / (1.0f + expf(-mag))) / (mag + 1e-8f);
        field[(size_t)(u * 128 + v) * 64 + c] =
            make_float4(Are * scale, Aim * scale, Bre * 0.1f, Bim * 0.1f);
    }
}

// ---- Kernel 2: weights fp32 (k,n) -> bf16 transposed (g,n,k) ----
__global__ void wprep_kernel(const float* __restrict__ Wf, const float* __restrict__ Wi,
                             const float* __restrict__ Wd, ushort* __restrict__ Wt) {
    const int idx = blockIdx.x * 256 + threadIdx.x;
    const int g = idx >> 14;
    const int r = idx & 16383;
    const int n = r >> 7, k = r & 127;
    const float* W = (g == 0) ? Wf : (g == 1) ? Wi : Wd;
    Wt[idx] = f2bf(W[k * 128 + n]);
}

// ---- Kernel 3: 1024-thread block, LDS-shared weights, 4 pixel-groups ----
__global__ __launch_bounds__(1024, 4) void main_kernel(
    const float* __restrict__ x,
    const float* __restrict__ bfv, const float* __restrict__ biv, const float* __restrict__ bdv,
    const float4* __restrict__ field,
    const ushort* __restrict__ Wt,
    float* __restrict__ out)
{
    extern __shared__ ushort smem[];
    ushort* wlds = smem;                                   // 96 KiB swizzled weights
    const int tid  = threadIdx.x;
    const int pg   = tid >> 8;          // pixel-group 0..3
    const int t2   = tid & 255;         // thread-in-group
    const int lane = tid & 63;
    const int cw   = t2 >> 6;           // wave-in-group 0..3
    const int l15  = lane & 15;
    const int lg   = lane >> 4;
    ushort* xb0 = smem + WLDS_USH + (pg * 2 + 0) * TILE_USH;
    ushort* xb1 = smem + WLDS_USH + (pg * 2 + 1) * TILE_USH;

    // ---- cooperative weight load with full 4-bit slot XOR swizzle ----
    // row = g*128+n (256 B), 16 slots of 16 B; dest slot = slot ^ (row & 15)
    // read (fixed g,s,ks): slot' = (4ks+lg) ^ l15 -> injective per 16-lane phase
    for (int m = tid; m < 6144; m += 1024) {
        const int row = m >> 4, slot = m & 15;
        uint4 val = *(const uint4*)(Wt + row * 128 + slot * 8);
        *(uint4*)(wlds + row * 128 + ((slot ^ (row & 15)) * 8)) = val;
    }

    const int c0 = l15 + 16 * cw;
    const float bia[3][2] = { { bfv[c0] + 2.0f, bfv[c0 + 64] + 2.0f },
                              { biv[c0],        biv[c0 + 64]        },
                              { bdv[c0],        bdv[c0 + 64]        } };

    // lane-constant swizzled weight addresses (byte offsets into wlds)
    unsigned wrb[3][2];
#pragma unroll
    for (int g = 0; g < 3; ++g)
#pragma unroll
        for (int s = 0; s < 2; ++s)
            wrb[g][s] = (unsigned)(g * 128 + l15 + 16 * (cw + 4 * s)) * 256u;
    unsigned wso[4];
#pragma unroll
    for (int ks = 0; ks < 4; ++ks)
        wso[ks] = (unsigned)((64 * ks + 16 * lg) ^ (16 * l15));
    const char* wbase = (const char*)wlds;

    const int hw0 = blockIdx.x * (PPBG * NGRP) + pg * PPBG;

    // 32-bit element offsets, SGPR bases
    unsigned soff = ((unsigned)(t2 >> 4) * HW_TOTAL + hw0) * C2 + (t2 & 15) * 8;
    unsigned foff = (unsigned)hw0 * 64 + c0;
    unsigned oof[4];
#pragma unroll
    for (int r = 0; r < 4; ++r)
        oof[r] = ((unsigned)(4 * lg + r) * HW_TOTAL + hw0) * C2 + c0;

    float4 qaA, qbA, qaB, qbB;   // 2-deep tile prefetch banks
    float4 fldA, fldB;           // field prefetch banks

    auto stage = [&](ushort* wb, const float4& qa, const float4& qb) {
        unsigned pk[4] = { pk2bf(qa.x, qa.y), pk2bf(qa.z, qa.w),
                           pk2bf(qb.x, qb.y), pk2bf(qb.z, qb.w) };
        *(uint4*)(wb + (t2 >> 4) * 136 + (t2 & 15) * 8) = *(uint4*)pk;
    };

    auto body = [&](int p, const ushort* rb, ushort* wb,
                    float4& qa, float4& qb, float4& fldbank) {
        // 1. same-pixel fp32 recurrence inputs (L2-hot; consumed after MFMA block)
        float xr4[4], xi4[4];
#pragma unroll
        for (int r = 0; r < 4; ++r) {
            xr4[r] = x[oof[r]];
            xi4[r] = x[oof[r] + 64];
        }

        // 2. stage pixel p+1 (data loaded 2 bodies ago)
        if (p + 1 < PPBG) stage(wb, qa, qb);

        // 3. refill tile bank with pixel p+3
        if (p + 3 < PPBG) {
            qa = *(const float4*)(x + soff);
            qb = *(const float4*)(x + soff + 4);
            soff += C2;
        }
        // 4. field: consume bank, refill with pixel p+2
        const float4 fld = fldbank;
        if (p + 2 < PPBG) { fldbank = field[foff]; foff += 64; }

        // 5. GEMM: 3 gates x 2 halves, K=128; A from tile LDS, B from weight LDS
        f32x4 acc[3][2];
#pragma unroll
        for (int g = 0; g < 3; ++g)
#pragma unroll
            for (int s = 0; s < 2; ++s) {
                const float b = bia[g][s];
                acc[g][s] = (f32x4){b, b, b, b};
            }
#pragma unroll
        for (int ks = 0; ks < 4; ++ks) {
            const bf16x8 af = *(const bf16x8*)(rb + l15 * 136 + 8 * lg + 32 * ks);
#pragma unroll
            for (int g = 0; g < 3; ++g)
#pragma unroll
                for (int s = 0; s < 2; ++s) {
                    const bf16x8 w = *(const bf16x8*)(wbase + wrb[g][s] + wso[ks]);
                    acc[g][s] = __builtin_amdgcn_mfma_f32_16x16x32_bf16(
                        af, w, acc[g][s], 0, 0, 0);
                }
        }

        // 6. gates + T=16 recurrence (matrix doubling); Br,Bi pre-scaled by 0.1
        const float Ar = fld.x, Ai = fld.y, Br = fld.z, Bi = fld.w;
#pragma unroll
        for (int r = 0; r < 4; ++r) {
            const float fg_r = fast_sigmoid(acc[0][0][r]);
            const float fg_i = fast_sigmoid(acc[0][1][r]);
            const float ig_r = fast_sigmoid(acc[1][0][r]);
            const float ig_i = fast_sigmoid(acc[1][1][r]);
            const float dl_r = fast_softplus(acc[2][0][r]);
            const float dl_i = fast_softplus(acc[2][1][r]);
            float vr = dl_r * ig_r * fmaf(Br, xr4[r], -Bi * xi4[r]);
            float vi = dl_i * ig_i * fmaf(Br, xi4[r],  Bi * xr4[r]);
            float a  = fg_r * Ar, bm = -(fg_r * Ai);
            float cm = fg_i * Ai, d  = fg_i * Ar;
#pragma unroll
            for (int j = 0; j < 4; ++j) {
                const float nvr = fmaf(a, vr, fmaf(bm, vi, vr));
                const float nvi = fmaf(cm, vr, fmaf(d, vi, vi));
                if (j < 3) {
                    const float trc = a + d, bc = bm * cm;
                    const float na = fmaf(a, a, bc), nd = fmaf(d, d, bc);
                    const float nb = bm * trc, nc = cm * trc;
                    a = na; bm = nb; cm = nc; d = nd;
                }
                vr = nvr; vi = nvi;
            }
            out[oof[r]]      = vr;
            out[oof[r] + 64] = vi;
            oof[r] += C2;
        }

        // 7. LDS-only barrier (global loads/stores stay in flight)
        block_sync_lds();
    };

    // ---- prologue: stage pixel 0, prefetch tiles 1,2 and fields 0,1 ----
    {
        float4 q0a = *(const float4*)(x + soff);
        float4 q0b = *(const float4*)(x + soff + 4);
        soff += C2;
        stage(xb0, q0a, q0b);
    }
    qaA = *(const float4*)(x + soff); qbA = *(const float4*)(x + soff + 4); soff += C2;
    qaB = *(const float4*)(x + soff); qbB = *(const float4*)(x + soff + 4); soff += C2;
    fldA = field[foff]; foff += 64;
    fldB = field[foff]; foff += 64;
    __syncthreads();   // one full barrier: weights + tile 0 staged

    for (int p = 0; p < PPBG; p += 2) {
        body(p,     xb0, xb1, qaA, qbA, fldA);
        body(p + 1, xb1, xb0, qaB, qbB, fldB);
    }
}

extern "C" void kernel_launch(void* const* d_in, const int* in_sizes, int n_in,
                              void* d_out, int out_size, void* d_ws, size_t ws_size,
                              hipStream_t stream) {
    const float* x      = (const float*)d_in[0];
    const float* Wf     = (const float*)d_in[1];
    const float* bf     = (const float*)d_in[2];
    const float* Wi     = (const float*)d_in[3];
    const float* bi     = (const float*)d_in[4];
    const float* Wd     = (const float*)d_in[5];
    const float* bd     = (const float*)d_in[6];
    const float* A_real = (const float*)d_in[7];
    const float* A_imag = (const float*)d_in[8];
    const float* B_real = (const float*)d_in[9];
    const float* B_imag = (const float*)d_in[10];

    float4* field = (float4*)d_ws;                                       // 16 MiB
    ushort* Wt = (ushort*)((char*)d_ws + (size_t)HW_TOTAL * 64 * 16);    // 96 KiB

    field_kernel<<<dim3(256), dim3(256), 0, stream>>>(A_real, A_imag, B_real, B_imag, field);
    wprep_kernel<<<dim3(192), dim3(256), 0, stream>>>(Wf, Wi, Wd, Wt);
    main_kernel<<<dim3(NBLK), dim3(1024), LDS_BYTES, stream>>>(x, bf, bi, bd, field, Wt, (float*)d_out);
}

// Round 11
// 105.266 us; speedup vs baseline: 1.3379x; 1.3379x over previous
//
#include <hip/hip_runtime.h>
#include <hip/hip_bf16.h>

#define HW_TOTAL 16384
#define C2 128
#define PPB 16
#define NBLK (HW_TOTAL / PPB)

typedef short bf16x8 __attribute__((ext_vector_type(8)));
typedef float f32x4 __attribute__((ext_vector_type(4)));

__device__ __forceinline__ unsigned pk2bf(float lo, float hi) {
    __hip_bfloat162 h = __float22bfloat162_rn(make_float2(lo, hi));
    union { __hip_bfloat162 h; unsigned u; } v; v.h = h;
    return v.u;
}
__device__ __forceinline__ unsigned short f2bf(float f) {
    union { float f; unsigned u; } v; v.f = f;
    unsigned r = v.u + 0x7FFFu + ((v.u >> 16) & 1u);
    return (unsigned short)(r >> 16);
}
__device__ __forceinline__ float fast_sigmoid(float x) {
    return __builtin_amdgcn_rcpf(1.0f + __expf(-x));
}
__device__ __forceinline__ float fast_softplus(float x) {
    return fmaxf(x, 0.0f) + __logf(1.0f + __expf(-fabsf(x)));
}

// ---- Kernel 1: separable DFT of padded 7x7 kernels -> field[hw][c] = (Ar,Ai,0.1*Br,0.1*Bi) ----
__global__ void field_kernel(const float* __restrict__ Ark, const float* __restrict__ Aik,
                             const float* __restrict__ Brk, const float* __restrict__ Bik,
                             float4* __restrict__ field) {
    __shared__ float2 tw[128];
    __shared__ float2 G[2][64][9];
    const int v = blockIdx.x >> 1;
    const int uhalf = blockIdx.x & 1;
    const int t = threadIdx.x;
    if (t < 128) {
        float ph = (float)t * (6.283185307179586f / 128.0f);
        tw[t] = make_float2(cosf(ph), sinf(ph));
    }
    __syncthreads();
    for (int e = t; e < 896; e += 256) {
        const int kern = (e >= 448) ? 1 : 0;
        const int rem = e - kern * 448;
        const int c = rem / 7, p = rem % 7;
        const float* kr = kern ? Brk : Ark;
        const float* ki = kern ? Bik : Aik;
        float gr = 0.f, gi = 0.f;
#pragma unroll
        for (int q = 0; q < 7; ++q) {
            const int idx = (v * (q + 60)) & 127;
            const float twr = tw[idx].x, twi = -tw[idx].y;
            const float ar = kr[c * 49 + p * 7 + q], ai = ki[c * 49 + p * 7 + q];
            gr += ar * twr - ai * twi;
            gi += ar * twi + ai * twr;
        }
        G[kern][c][p] = make_float2(gr, gi);
    }
    __syncthreads();
    const int c = t & 63, ug = t >> 6;
    float2 gA[7], gB[7];
#pragma unroll
    for (int p = 0; p < 7; ++p) { gA[p] = G[0][c][p]; gB[p] = G[1][c][p]; }
    for (int k = 0; k < 16; ++k) {
        const int u = uhalf * 64 + ug * 16 + k;
        float Are = 0.f, Aim = 0.f, Bre = 0.f, Bim = 0.f;
#pragma unroll
        for (int p = 0; p < 7; ++p) {
            const int idx = (u * (p + 60)) & 127;
            const float twr = tw[idx].x, twi = -tw[idx].y;
            Are += gA[p].x * twr - gA[p].y * twi;
            Aim += gA[p].x * twi + gA[p].y * twr;
            Bre += gB[p].x * twr - gB[p].y * twi;
            Bim += gB[p].x * twi + gB[p].y * twr;
        }
        const float mag = sqrtf(Are * Are + Aim * Aim + 1e-8f);
        const float scale = 0.95f * (1.0f / (1.0f + expf(-mag))) / (mag + 1e-8f);
        field[(size_t)(u * 128 + v) * 64 + c] =
            make_float4(Are * scale, Aim * scale, Bre * 0.1f, Bim * 0.1f);
    }
}

// ---- Kernel 2: weights fp32 (k,n) -> bf16 transposed (g,n,k) ----
__global__ void wprep_kernel(const float* __restrict__ Wf, const float* __restrict__ Wi,
                             const float* __restrict__ Wd, ushort* __restrict__ Wt) {
    const int idx = blockIdx.x * 256 + threadIdx.x;
    const int g = idx >> 14;
    const int r = idx & 16383;
    const int n = r >> 7, k = r & 127;
    const float* W = (g == 0) ? Wf : (g == 1) ? Wi : Wd;
    Wt[idx] = f2bf(W[k * 128 + n]);
}

// ---- Kernel 3: R4 numerics, 2 pixels per barrier (4 LDS buffer pairs) ----
__global__ __launch_bounds__(256, 2) void main_kernel(
    const float* __restrict__ x,
    const float* __restrict__ bfv, const float* __restrict__ biv, const float* __restrict__ bdv,
    const float4* __restrict__ field,
    const ushort* __restrict__ Wt,
    float* __restrict__ out)
{
    __shared__ float  xsf[4][16][132];   // fp32 tiles (recurrence inputs)
    __shared__ ushort xsb[4][16][136];   // bf16 tiles (MFMA A-frags)
    const int tid  = threadIdx.x;
    const int lane = tid & 63;
    const int wave = tid >> 6;
    const int l15  = lane & 15;
    const int lg   = lane >> 4;

    // persistent weight fragments
    bf16x8 wf[3][2][4];
#pragma unroll
    for (int g = 0; g < 3; ++g)
#pragma unroll
        for (int s = 0; s < 2; ++s) {
            const int n = l15 + 16 * (wave + 4 * s);
#pragma unroll
            for (int ks = 0; ks < 4; ++ks)
                wf[g][s][ks] = *(const bf16x8*)(Wt + ((g * 128 + n) * 128 + 32 * ks + 8 * lg));
        }

    const int c0 = l15 + 16 * wave;
    const float bia[3][2] = { { bfv[c0] + 2.0f, bfv[c0 + 64] + 2.0f },
                              { biv[c0],        biv[c0 + 64]        },
                              { bdv[c0],        bdv[c0 + 64]        } };

    const int srow = tid >> 4;
    const int scol = (tid & 15) * 8;
    const int hw0 = blockIdx.x * PPB;

    const float* srcp = x + ((size_t)srow * HW_TOTAL + hw0) * C2 + scol;
    const float4* fldp = field + (size_t)hw0 * 64 + c0;
    float* op[4];
#pragma unroll
    for (int r = 0; r < 4; ++r)
        op[r] = out + ((size_t)(4 * lg + r) * HW_TOTAL + hw0) * C2 + c0;

    f32x4 accA[3][2], accB[3][2];
    float4 q0a, q0b, q1a, q1b;   // tile prefetch banks for 2 pixels
    float4 fldA, fldB;           // field banks for 2 pixels

    auto pref2 = [&](float4& a, float4& b) {
        a = *(const float4*)srcp;
        b = *(const float4*)(srcp + 4);
        srcp += C2;
    };
    auto stage = [&](float (*wbF)[132], ushort (*wbB)[136], const float4& qa, const float4& qb) {
        *(float4*)&wbF[srow][scol]     = qa;
        *(float4*)&wbF[srow][scol + 4] = qb;
        unsigned pk[4] = { pk2bf(qa.x, qa.y), pk2bf(qa.z, qa.w),
                           pk2bf(qb.x, qb.y), pk2bf(qb.z, qb.w) };
        *(uint4*)&wbB[srow][scol] = *(uint4*)pk;
    };
    auto do_mfma = [&](f32x4 (&acc)[3][2], const bf16x8 (&af)[4]) {
#pragma unroll
        for (int g = 0; g < 3; ++g)
#pragma unroll
            for (int s = 0; s < 2; ++s) {
                const float b = bia[g][s];
                acc[g][s] = (f32x4){b, b, b, b};
            }
#pragma unroll
        for (int ks = 0; ks < 4; ++ks)
#pragma unroll
            for (int g = 0; g < 3; ++g)
#pragma unroll
                for (int s = 0; s < 2; ++s)
                    acc[g][s] = __builtin_amdgcn_mfma_f32_16x16x32_bf16(
                        af[ks], wf[g][s][ks], acc[g][s], 0, 0, 0);
    };
    auto finish = [&](const f32x4 (&acc)[3][2], const float4& fldv,
                      const float (&xr4)[4], const float (&xi4)[4]) {
        const float Ar = fldv.x, Ai = fldv.y, Br = fldv.z, Bi = fldv.w;
#pragma unroll
        for (int r = 0; r < 4; ++r) {
            const float fg_r = fast_sigmoid(acc[0][0][r]);
            const float fg_i = fast_sigmoid(acc[0][1][r]);
            const float ig_r = fast_sigmoid(acc[1][0][r]);
            const float ig_i = fast_sigmoid(acc[1][1][r]);
            const float dl_r = fast_softplus(acc[2][0][r]);
            const float dl_i = fast_softplus(acc[2][1][r]);
            float vr = dl_r * ig_r * fmaf(Br, xr4[r], -Bi * xi4[r]);
            float vi = dl_i * ig_i * fmaf(Br, xi4[r],  Bi * xr4[r]);
            float a  = fg_r * Ar, bm = -(fg_r * Ai);
            float cm = fg_i * Ai, d  = fg_i * Ar;
#pragma unroll
            for (int j = 0; j < 4; ++j) {
                const float nvr = fmaf(a, vr, fmaf(bm, vi, vr));
                const float nvi = fmaf(cm, vr, fmaf(d, vi, vi));
                if (j < 3) {
                    const float trc = a + d, bc = bm * cm;
                    const float na = fmaf(a, a, bc), nd = fmaf(d, d, bc);
                    const float nb = bm * trc, nc = cm * trc;
                    a = na; bm = nb; cm = nc; d = nd;
                }
                vr = nvr; vi = nvi;
            }
            op[r][0]  = vr;
            op[r][64] = vi;
            op[r] += C2;
        }
    };

    // super-iteration: pixels p, p+1 from read pair; stage p+2,p+3 into write pair
    auto super = [&](int p,
                     const float (*rF0)[132], const ushort (*rB0)[136],
                     const float (*rF1)[132], const ushort (*rB1)[136],
                     float (*wF0)[132], ushort (*wB0)[136],
                     float (*wF1)[132], ushort (*wB1)[136]) {
        // 1. LDS reads for both pixels
        bf16x8 afA[4], afB[4];
#pragma unroll
        for (int ks = 0; ks < 4; ++ks) {
            afA[ks] = *(const bf16x8*)&rB0[l15][8 * lg + 32 * ks];
            afB[ks] = *(const bf16x8*)&rB1[l15][8 * lg + 32 * ks];
        }
        float xrA[4], xiA[4], xrB[4], xiB[4];
#pragma unroll
        for (int r = 0; r < 4; ++r) {
            xrA[r] = rF0[4 * lg + r][c0];
            xiA[r] = rF0[4 * lg + r][c0 + 64];
            xrB[r] = rF1[4 * lg + r][c0];
            xiB[r] = rF1[4 * lg + r][c0 + 64];
        }
        const float4 fA = fldA, fB = fldB;

        // 2. stage pixels p+2, p+3 (reg data loaded one super-iter ago)
        if (p + 2 < PPB) {
            stage(wF0, wB0, q0a, q0b);
            stage(wF1, wB1, q1a, q1b);
        }
        // 3. refill banks: tiles p+4,p+5 ; fields p+2,p+3
        if (p + 4 < PPB) { pref2(q0a, q0b); pref2(q1a, q1b); }
        if (p + 2 < PPB) { fldA = fldp[0]; fldB = fldp[64]; fldp += 128; }

        // 4. GEMMs for both pixels
        do_mfma(accA, afA);
        do_mfma(accB, afB);

        // 5. epilogues (scalar, R4-verbatim numerics)
        finish(accA, fA, xrA, xiA);
        finish(accB, fB, xrB, xiB);

        // 6. ONE barrier per two pixels
        __syncthreads();
    };

    // prologue: stage pixels 0,1; prefetch tiles 2,3; fields 0,1
    pref2(q0a, q0b); pref2(q1a, q1b);
    stage(xsf[0], xsb[0], q0a, q0b);
    stage(xsf[1], xsb[1], q1a, q1b);
    pref2(q0a, q0b); pref2(q1a, q1b);
    fldA = fldp[0]; fldB = fldp[64]; fldp += 128;
    __syncthreads();

    for (int s2 = 0; s2 < PPB; s2 += 4) {
        super(s2,     xsf[0], xsb[0], xsf[1], xsb[1], xsf[2], xsb[2], xsf[3], xsb[3]);
        super(s2 + 2, xsf[2], xsb[2], xsf[3], xsb[3], xsf[0], xsb[0], xsf[1], xsb[1]);
    }
}

extern "C" void kernel_launch(void* const* d_in, const int* in_sizes, int n_in,
                              void* d_out, int out_size, void* d_ws, size_t ws_size,
                              hipStream_t stream) {
    const float* x      = (const float*)d_in[0];
    const float* Wf     = (const float*)d_in[1];
    const float* bf     = (const float*)d_in[2];
    const float* Wi     = (const float*)d_in[3];
    const float* bi     = (const float*)d_in[4];
    const float* Wd     = (const float*)d_in[5];
    const float* bd     = (const float*)d_in[6];
    const float* A_real = (const float*)d_in[7];
    const float* A_imag = (const float*)d_in[8];
    const float* B_real = (const float*)d_in[9];
    const float* B_imag = (const float*)d_in[10];

    float4* field = (float4*)d_ws;                                       // 16 MiB
    ushort* Wt = (ushort*)((char*)d_ws + (size_t)HW_TOTAL * 64 * 16);    // 96 KiB

    field_kernel<<<dim3(256), dim3(256), 0, stream>>>(A_real, A_imag, B_real, B_imag, field);
    wprep_kernel<<<dim3(192), dim3(256), 0, stream>>>(Wf, Wi, Wd, Wt);
    main_kernel<<<dim3(NBLK), dim3(256), 0, stream>>>(x, bf, bi, bd, field, Wt, (float*)d_out);
}

// Round 12
// 103.766 us; speedup vs baseline: 1.3573x; 1.0145x over previous
//
#include <hip/hip_runtime.h>
#include <hip/hip_bf16.h>

#define HW_TOTAL 16384
#define C2 128
#define PPB 16
#define NBLK (HW_TOTAL / PPB)

typedef short bf16x8 __attribute__((ext_vector_type(8)));
typedef float f32x4 __attribute__((ext_vector_type(4)));

__device__ __forceinline__ unsigned pk2bf(float lo, float hi) {
    __hip_bfloat162 h = __float22bfloat162_rn(make_float2(lo, hi));
    union { __hip_bfloat162 h; unsigned u; } v; v.h = h;
    return v.u;
}
__device__ __forceinline__ unsigned short f2bf(float f) {
    union { float f; unsigned u; } v; v.f = f;
    unsigned r = v.u + 0x7FFFu + ((v.u >> 16) & 1u);
    return (unsigned short)(r >> 16);
}
__device__ __forceinline__ float fast_sigmoid(float x) {
    return __builtin_amdgcn_rcpf(1.0f + __expf(-x));
}
__device__ __forceinline__ float fast_softplus(float x) {
    return fmaxf(x, 0.0f) + __logf(1.0f + __expf(-fabsf(x)));
}
// barrier WITHOUT vmcnt(0) drain: LDS is the only cross-thread medium in the loop.
__device__ __forceinline__ void block_sync_lds() {
    asm volatile("s_waitcnt lgkmcnt(0)\n\ts_barrier" ::: "memory");
}

// ---- Kernel 1: separable DFT of padded 7x7 kernels -> field[hw][c] = (Ar,Ai,0.1*Br,0.1*Bi) ----
__global__ void field_kernel(const float* __restrict__ Ark, const float* __restrict__ Aik,
                             const float* __restrict__ Brk, const float* __restrict__ Bik,
                             float4* __restrict__ field) {
    __shared__ float2 tw[128];
    __shared__ float2 G[2][64][9];
    const int v = blockIdx.x >> 1;
    const int uhalf = blockIdx.x & 1;
    const int t = threadIdx.x;
    if (t < 128) {
        float ph = (float)t * (6.283185307179586f / 128.0f);
        tw[t] = make_float2(cosf(ph), sinf(ph));
    }
    __syncthreads();
    for (int e = t; e < 896; e += 256) {
        const int kern = (e >= 448) ? 1 : 0;
        const int rem = e - kern * 448;
        const int c = rem / 7, p = rem % 7;
        const float* kr = kern ? Brk : Ark;
        const float* ki = kern ? Bik : Aik;
        float gr = 0.f, gi = 0.f;
#pragma unroll
        for (int q = 0; q < 7; ++q) {
            const int idx = (v * (q + 60)) & 127;
            const float twr = tw[idx].x, twi = -tw[idx].y;
            const float ar = kr[c * 49 + p * 7 + q], ai = ki[c * 49 + p * 7 + q];
            gr += ar * twr - ai * twi;
            gi += ar * twi + ai * twr;
        }
        G[kern][c][p] = make_float2(gr, gi);
    }
    __syncthreads();
    const int c = t & 63, ug = t >> 6;
    float2 gA[7], gB[7];
#pragma unroll
    for (int p = 0; p < 7; ++p) { gA[p] = G[0][c][p]; gB[p] = G[1][c][p]; }
    for (int k = 0; k < 16; ++k) {
        const int u = uhalf * 64 + ug * 16 + k;
        float Are = 0.f, Aim = 0.f, Bre = 0.f, Bim = 0.f;
#pragma unroll
        for (int p = 0; p < 7; ++p) {
            const int idx = (u * (p + 60)) & 127;
            const float twr = tw[idx].x, twi = -tw[idx].y;
            Are += gA[p].x * twr - gA[p].y * twi;
            Aim += gA[p].x * twi + gA[p].y * twr;
            Bre += gB[p].x * twr - gB[p].y * twi;
            Bim += gB[p].x * twi + gB[p].y * twr;
        }
        const float mag = sqrtf(Are * Are + Aim * Aim + 1e-8f);
        const float scale = 0.95f * (1.0f / (1.0f + expf(-mag))) / (mag + 1e-8f);
        field[(size_t)(u * 128 + v) * 64 + c] =
            make_float4(Are * scale, Aim * scale, Bre * 0.1f, Bim * 0.1f);
    }
}

// ---- Kernel 2: weights fp32 (k,n) -> bf16 transposed (g,n,k) ----
__global__ void wprep_kernel(const float* __restrict__ Wf, const float* __restrict__ Wi,
                             const float* __restrict__ Wd, ushort* __restrict__ Wt) {
    const int idx = blockIdx.x * 256 + threadIdx.x;
    const int g = idx >> 14;
    const int r = idx & 16383;
    const int n = r >> 7, k = r & 127;
    const float* W = (g == 0) ? Wf : (g == 1) ? Wi : Wd;
    Wt[idx] = f2bf(W[k * 128 + n]);
}

// ---- Kernel 3: 512-thread block, 8 waves split over channel halves, occupancy 4 ----
__global__ __launch_bounds__(512, 4) void main_kernel(
    const float* __restrict__ x,
    const float* __restrict__ bfv, const float* __restrict__ biv, const float* __restrict__ bdv,
    const float4* __restrict__ field,
    const ushort* __restrict__ Wt,
    float* __restrict__ out)
{
    __shared__ float  xsf[2][16][132];       // fp32 tile (recurrence inputs)
    __shared__ ushort xsb[2][16][136];       // bf16 tile (MFMA A-frags)
    __shared__ float  glf[2][2][64][19];     // fg exchange  [buf][s][c2][row pad19]
    __shared__ float  glg[2][2][64][19];     // ig*dl exchange

    const int tid  = threadIdx.x;
    const int w    = tid >> 6;       // wave 0..7
    const int lane = tid & 63;
    const int s    = w >> 2;         // 0: real half, 1: imag half
    const int wq   = w & 3;          // 16-col sub-block
    const int l15  = lane & 15;
    const int lg   = lane >> 4;

    // persistent weight fragments: 3 gates x 4 k-steps, ONE column-block -> 48 VGPR
    bf16x8 wf[3][4];
    {
        const int n = l15 + 16 * (wq + 4 * s);
#pragma unroll
        for (int g = 0; g < 3; ++g)
#pragma unroll
            for (int ks = 0; ks < 4; ++ks)
                wf[g][ks] = *(const bf16x8*)(Wt + ((g * 128 + n) * 128 + 32 * ks + 8 * lg));
    }

    const int c2 = l15 + 16 * wq;            // channel-pair index 0..63
    const int cfull = c2 + 64 * s;           // actual gate column
    const float bia0 = bfv[cfull] + 2.0f;
    const float bia1 = biv[cfull];
    const float bia2 = bdv[cfull];

    // recurrence elements: (row0, c2) and (row0+4, c2)
    const int row0 = lg + 8 * s;             // rows: lg + {0,4} + 8s covers 0..15

    // staging: 512 threads, 1 float4 each
    const int trow = tid >> 5;
    const int tcol = (tid & 31) * 4;

    const int hw0 = blockIdx.x * PPB;
    unsigned soff = ((unsigned)trow * HW_TOTAL + hw0) * C2 + tcol;
    unsigned foff = (unsigned)hw0 * 64 + c2;
    float* po0 = out + ((size_t)row0 * HW_TOTAL + hw0) * C2 + c2;
    float* po1 = out + ((size_t)(row0 + 4) * HW_TOTAL + hw0) * C2 + c2;

    float4 qa;     // tile prefetch bank (1 pixel ahead)
    float4 fld;    // field prefetch bank

    auto stage = [&](int buf, const float4& q) {
        *(float4*)&xsf[buf][trow][tcol] = q;
        uint2 pk = { pk2bf(q.x, q.y), pk2bf(q.z, q.w) };
        *(uint2*)&xsb[buf][trow][tcol] = pk;
    };

    // prologue: stage pixel 0, prefetch tile 1 + field 0
    qa = *(const float4*)(x + soff); soff += C2;
    stage(0, qa);
    qa = *(const float4*)(x + soff); soff += C2;
    fld = field[foff]; foff += 64;
    block_sync_lds();

    for (int p = 0; p < PPB; ++p) {
        const int buf = p & 1;

        // 1. LDS reads for pixel p: A-frags + fp32 recurrence inputs
        bf16x8 af[4];
#pragma unroll
        for (int ks = 0; ks < 4; ++ks)
            af[ks] = *(const bf16x8*)&xsb[buf][l15][8 * lg + 32 * ks];
        const float xr0 = xsf[buf][row0][c2],     xi0 = xsf[buf][row0][c2 + 64];
        const float xr1 = xsf[buf][row0 + 4][c2], xi1 = xsf[buf][row0 + 4][c2 + 64];

        // 2. stage pixel p+1 (regs loaded last iter); prefetch tile p+2, field p+1
        if (p + 1 < PPB) stage(buf ^ 1, qa);
        if (p + 2 < PPB) { qa = *(const float4*)(x + soff); soff += C2; }
        const float4 fldc = fld;
        if (p + 1 < PPB) { fld = field[foff]; foff += 64; }

        // 3. GEMM: 3 gates x 1 half, K=128, bias in C-operand
        f32x4 acc[3];
        acc[0] = (f32x4){bia0, bia0, bia0, bia0};
        acc[1] = (f32x4){bia1, bia1, bia1, bia1};
        acc[2] = (f32x4){bia2, bia2, bia2, bia2};
#pragma unroll
        for (int ks = 0; ks < 4; ++ks)
#pragma unroll
            for (int g = 0; g < 3; ++g)
                acc[g] = __builtin_amdgcn_mfma_f32_16x16x32_bf16(
                    af[ks], wf[g][ks], acc[g], 0, 0, 0);

        // 4. gates for 4 rows of my column; write to exchange LDS
#pragma unroll
        for (int r = 0; r < 4; ++r) {
            const float fg = fast_sigmoid(acc[0][r]);
            const float gi = fast_sigmoid(acc[1][r]) * fast_softplus(acc[2][r]);
            glf[buf][s][c2][4 * lg + r] = fg;
            glg[buf][s][c2][4 * lg + r] = gi;
        }

        block_sync_lds();   // gates(p) visible; tile(p+1) visible

        // 5. recurrence for 2 (row,c2) elements; Br,Bi pre-scaled by 0.1
        const float Ar = fldc.x, Ai = fldc.y, Br = fldc.z, Bi = fldc.w;
#pragma unroll
        for (int k = 0; k < 2; ++k) {
            const int row = row0 + 4 * k;
            const float fg_r = glf[buf][0][c2][row];
            const float fg_i = glf[buf][1][c2][row];
            const float gi_r = glg[buf][0][c2][row];
            const float gi_i = glg[buf][1][c2][row];
            const float xr = k ? xr1 : xr0;
            const float xi = k ? xi1 : xi0;
            float vr = gi_r * fmaf(Br, xr, -Bi * xi);
            float vi = gi_i * fmaf(Br, xi,  Bi * xr);
            float a  = fg_r * Ar, bm = -(fg_r * Ai);
            float cm = fg_i * Ai, d  = fg_i * Ar;
#pragma unroll
            for (int j = 0; j < 4; ++j) {
                const float nvr = fmaf(a, vr, fmaf(bm, vi, vr));
                const float nvi = fmaf(cm, vr, fmaf(d, vi, vi));
                if (j < 3) {
                    const float trc = a + d, bc = bm * cm;
                    const float na = fmaf(a, a, bc), nd = fmaf(d, d, bc);
                    const float nb = bm * trc, nc = cm * trc;
                    a = na; bm = nb; cm = nc; d = nd;
                }
                vr = nvr; vi = nvi;
            }
            if (k == 0) { po0[0] = vr; po0[64] = vi; po0 += C2; }
            else        { po1[0] = vr; po1[64] = vi; po1 += C2; }
        }
    }
}

extern "C" void kernel_launch(void* const* d_in, const int* in_sizes, int n_in,
                              void* d_out, int out_size, void* d_ws, size_t ws_size,
                              hipStream_t stream) {
    const float* x      = (const float*)d_in[0];
    const float* Wf     = (const float*)d_in[1];
    const float* bf     = (const float*)d_in[2];
    const float* Wi     = (const float*)d_in[3];
    const float* bi     = (const float*)d_in[4];
    const float* Wd     = (const float*)d_in[5];
    const float* bd     = (const float*)d_in[6];
    const float* A_real = (const float*)d_in[7];
    const float* A_imag = (const float*)d_in[8];
    const float* B_real = (const float*)d_in[9];
    const float* B_imag = (const float*)d_in[10];

    float4* field = (float4*)d_ws;                                       // 16 MiB
    ushort* Wt = (ushort*)((char*)d_ws + (size_t)HW_TOTAL * 64 * 16);    // 96 KiB

    field_kernel<<<dim3(256), dim3(256), 0, stream>>>(A_real, A_imag, B_real, B_imag, field);
    wprep_kernel<<<dim3(192), dim3(256), 0, stream>>>(Wf, Wi, Wd, Wt);
    main_kernel<<<dim3(NBLK), dim3(512), 0, stream>>>(x, bf, bi, bd, field, Wt, (float*)d_out);
}